// Round 7
// baseline (705.485 us; speedup 1.0000x reference)
//
#include <hip/hip_runtime.h>

#define N_NODES 10000
#define N_EDGES 160000
#define DEPTH   10
#define NBLK    256
#define NTHR    512
#define GRPA    64                // blocks 0..63: weight chain
#define GRPB    (NBLK - GRPA)     // blocks 64..255: CSR + agg6
#define RPAD    10048

// barrier counter indices (32-int array, pre-zeroed each call)
#define CA 0    // 11 barriers, weight-chain group (expected GRPA)
#define CB 12   // 4 barriers, CSR group (expected GRPB)
#define CF 16   // 11 barriers, full grid (expected NBLK)

// ============================================================================
// Algebraic collapse (verified R6, absmax 0.0):
//   out = A^10 x1 w~ + sum_k gamma_k A^(10-k) 1 + b_out
//   w~ = W1..W10 Wout,  gamma_k = b_k . (W_{k+1}..W10 Wout)
// R7: everything in ONE persistent kernel; weight chain || CSR build.
// ============================================================================

__global__ void zero_ctr_kernel(int* c) {
    if (threadIdx.x < 32) c[threadIdx.x] = 0;
}

__device__ inline void gbar(int* c, int expected) {
    __syncthreads();
    if (threadIdx.x == 0) {
        __threadfence();  // release: publish prior writes device-wide
        __hip_atomic_fetch_add(c, 1, __ATOMIC_ACQ_REL, __HIP_MEMORY_SCOPE_AGENT);
        while (__hip_atomic_load(c, __ATOMIC_ACQUIRE, __HIP_MEMORY_SCOPE_AGENT) < expected)
            __builtin_amdgcn_s_sleep(8);
        __threadfence();  // acquire: discard stale cached lines
    }
    __syncthreads();
}

__device__ inline float wave_reduce(float s) {
#pragma unroll
    for (int off = 32; off > 0; off >>= 1) s += __shfl_down(s, off, 64);
    return s;
}

__global__ __launch_bounds__(NTHR) void mega_kernel(
    const float* __restrict__ features, const float* __restrict__ W_in,
    const float* __restrict__ b_in, const float* __restrict__ Ws,
    const float* __restrict__ bs, const float* __restrict__ W_out,
    const float* __restrict__ b_out, const int* __restrict__ src,
    const int* __restrict__ dst, float* __restrict__ out,
    int* __restrict__ ctr, int* __restrict__ deg, int* __restrict__ row_ptr,
    int* __restrict__ cursor, int* __restrict__ esrc, float* __restrict__ agg6,
    float* __restrict__ v,      // [2][512]
    float* __restrict__ gamma,  // [10]
    float* __restrict__ r) {    // [2][RPAD]
    __shared__ int sums[NTHR];
    const int blk = blockIdx.x;
    const int tid = threadIdx.x;

    if (blk < GRPA) {
        // ================= group A: backward weight chain =================
        const int g = blk * NTHR + tid;      // 0..32767
        const int w = g >> 6;                // 0..511 (one row per wave)
        const int lane = g & 63;
        if (g < 512) v[g] = W_out[g];        // v[0] = W_out column
        gbar(ctr + CA + 0, GRPA);
        int cur = 0;
        for (int l = DEPTH - 1; l >= 0; l--) {
            const float* Wrow = Ws + (size_t)l * 512 * 512 + (size_t)w * 512;
            const float* vin = v + cur * 512;
            float s = 0.f;
#pragma unroll
            for (int c = 0; c < 8; c++) s += Wrow[lane + c * 64] * vin[lane + c * 64];
            s = wave_reduce(s);
            if (lane == 0) v[(cur ^ 1) * 512 + w] = s;
            if (w == 511) {  // gamma[l] = bs[l] . vin
                const float* bl = bs + (size_t)l * 512;
                float t = 0.f;
#pragma unroll
                for (int c = 0; c < 8; c++) t += bl[lane + c * 64] * vin[lane + c * 64];
                t = wave_reduce(t);
                if (lane == 0) gamma[l] = t;
            }
            gbar(ctr + CA + 1 + (DEPTH - 1 - l), GRPA);
            cur ^= 1;
        }
        // w~ now in v[0..511]
    } else {
        // ================= group B: CSR build + agg6 =================
        const int g = (blk - GRPA) * NTHR + tid;  // 0..98303
        if (g < N_NODES) deg[g] = 0;
        gbar(ctr + CB + 0, GRPB);
        for (int i = g; i < N_EDGES; i += GRPB * NTHR) atomicAdd(&deg[dst[i]], 1);
        gbar(ctr + CB + 1, GRPB);
        if (blk == GRPA) {
            // exclusive scan of deg[10000] by this block alone (512 thr x 20)
            const int CH = 20;
            int base = tid * CH;
            int local[CH];
            int s = 0;
#pragma unroll
            for (int i = 0; i < CH; i++) {
                int idx = base + i;
                int vv = (idx < N_NODES) ? deg[idx] : 0;
                local[i] = s;
                s += vv;
            }
            sums[tid] = s;
            __syncthreads();
            for (int off = 1; off < NTHR; off <<= 1) {
                int vv = (tid >= off) ? sums[tid - off] : 0;
                __syncthreads();
                sums[tid] += vv;
                __syncthreads();
            }
            int cb = (tid > 0) ? sums[tid - 1] : 0;
#pragma unroll
            for (int i = 0; i < CH; i++) {
                int idx = base + i;
                if (idx < N_NODES) {
                    int vv = cb + local[i];
                    row_ptr[idx] = vv;
                    cursor[idx] = vv;
                }
            }
            if (tid == NTHR - 1) row_ptr[N_NODES] = sums[NTHR - 1];
        }
        gbar(ctr + CB + 2, GRPB);
        for (int i = g; i < N_EDGES; i += GRPB * NTHR) {
            int p = atomicAdd(&cursor[dst[i]], 1);
            esrc[p] = src[i];
        }
        gbar(ctr + CB + 3, GRPB);
        // agg6: 8 lanes per node (6 active)
        {
            int node = g >> 3, c = g & 7;
            if (node < N_NODES && c < 6) {
                int s0 = row_ptr[node], e0 = row_ptr[node + 1];
                float a0 = 0.f, a1 = 0.f;
                int e = s0;
                for (; e + 2 <= e0; e += 2) {
                    a0 += features[esrc[e] * 6 + c];
                    a1 += features[esrc[e + 1] * 6 + c];
                }
                if (e < e0) a0 += features[esrc[e] * 6 + c];
                agg6[node * 6 + c] = a0 + a1;
            }
        }
    }

    // ================= join =================
    gbar(ctr + CF + 0, NBLK);

    // ================= input_z: r[0][n] = relu(agg6 W_in + b_in) . w~ =========
    {
        const int g = blk * NTHR + tid;
        const int wgid = g >> 6;
        const int lane = g & 63;
        const int nw = (NBLK * NTHR) >> 6;  // 2048 waves
        for (int node = wgid; node < N_NODES; node += nw) {
            float a[6];
#pragma unroll
            for (int k = 0; k < 6; k++) a[k] = agg6[node * 6 + k];
            float s = 0.f;
#pragma unroll
            for (int c8 = 0; c8 < 8; c8++) {
                int j = lane + c8 * 64;
                float t = b_in[j];
#pragma unroll
                for (int k = 0; k < 6; k++) t += a[k] * W_in[k * 512 + j];
                s += fmaxf(t, 0.f) * v[j];  // w~ = v[0]
            }
            s = wave_reduce(s);
            if (lane == 0) r[node] = s;
        }
    }
    gbar(ctr + CF + 1, NBLK);

    // ================= Horner: r <- A r + gamma[l] ; last adds b_out =========
    {
        const int g = blk * NTHR + tid;
        const int node = g >> 3;    // 8 lanes per node
        const int l8 = g & 7;
        int start = 0, end = 0;
        if (node < N_NODES) {
            start = row_ptr[node];
            end = row_ptr[node + 1];
        }
        int cur = 0;
        for (int l = 0; l < DEPTH; l++) {
            const float* rin = r + cur * RPAD;
            float s = 0.f;
            if (node < N_NODES) {
                for (int e = start + l8; e < end; e += 8) s += rin[esrc[e]];
            }
            s += __shfl_xor(s, 1, 64);
            s += __shfl_xor(s, 2, 64);
            s += __shfl_xor(s, 4, 64);
            if (node < N_NODES && l8 == 0) {
                float res = s + gamma[l];
                if (l == DEPTH - 1) out[node] = res + b_out[0];
                else r[(cur ^ 1) * RPAD + node] = res;
            }
            if (l < DEPTH - 1) gbar(ctr + CF + 2 + l, NBLK);
            cur ^= 1;
        }
    }
}

// ---------------- launch ----------------

extern "C" void kernel_launch(void* const* d_in, const int* in_sizes, int n_in,
                              void* d_out, int out_size, void* d_ws, size_t ws_size,
                              hipStream_t stream) {
    const float* features = (const float*)d_in[0];  // [10000, 6]
    const float* W_in     = (const float*)d_in[1];  // [6, 512]
    const float* b_in     = (const float*)d_in[2];  // [512]
    const float* Ws       = (const float*)d_in[3];  // [10, 512, 512]
    const float* bs       = (const float*)d_in[4];  // [10, 512]
    const float* W_out    = (const float*)d_in[5];  // [512, 1]
    const float* b_out    = (const float*)d_in[6];  // [1]
    const int*   src      = (const int*)d_in[7];    // [160000]
    const int*   dst      = (const int*)d_in[8];    // [160000]
    float* out = (float*)d_out;                     // [10000]

    char* p = (char*)d_ws;
    auto alloc = [&](size_t bytes) {
        char* r = p;
        p += (bytes + 255) & ~size_t(255);
        return r;
    };
    int* ctr     = (int*)alloc(32 * 4);
    int* deg     = (int*)alloc((size_t)N_NODES * 4);
    int* row_ptr = (int*)alloc((size_t)(N_NODES + 1) * 4);
    int* cursor  = (int*)alloc((size_t)N_NODES * 4);
    int* esrc    = (int*)alloc((size_t)N_EDGES * 4);
    float* agg6  = (float*)alloc((size_t)N_NODES * 6 * 4);
    float* v     = (float*)alloc(2 * 512 * 4);
    float* gamma = (float*)alloc(DEPTH * 4);
    float* r     = (float*)alloc((size_t)2 * RPAD * 4);

    zero_ctr_kernel<<<1, 64, 0, stream>>>(ctr);
    mega_kernel<<<NBLK, NTHR, 0, stream>>>(features, W_in, b_in, Ws, bs, W_out,
                                           b_out, src, dst, out, ctr, deg,
                                           row_ptr, cursor, esrc, agg6, v,
                                           gamma, r);
}

// Round 8
// 406.325 us; speedup vs baseline: 1.7363x; 1.7363x over previous
//
#include <hip/hip_runtime.h>

#define N_NODES 10000
#define N_EDGES 160000
#define DEPTH   10
#define NBLK    256
#define NTHR    512
#define GRPA    64                // blocks 0..63: weight chain
#define GRPB    (NBLK - GRPA)     // blocks 64..255: CSR + agg6
#define RPAD    10048

// Barrier instances: each occupies a 64-byte line: [0]=count, [8]=flag.
// CA 0..9 (group A: v-init + 9 inter-step), CB 10..13 (group B),
// CF 14..24 (join, post-input_z, 9 Horner inter-hop). 32 lines total.
#define BAR_LINE 16   // ints per line
#define CA 0
#define CB 10
#define CF 14
#define NBAR 32

// ============================================================================
// Algebraic collapse (verified R6/R7, absmax 0.0):
//   out = A^10 x1 w~ + sum_k gamma_k A^(10-k) 1 + b_out
//   w~ = W1..W10 Wout,  gamma_k = b_k . (W_{k+1}..W10 Wout)
// R8: persistent kernel with RELAXED-spin flag barriers (R7's acquire-spin
// caused per-iteration L2 invalidation storms -> 26 us/barrier).
// ============================================================================

__global__ void zero_ctr_kernel(int* c) {
    int i = threadIdx.x;
    if (i < NBAR * BAR_LINE) c[i] = 0;
}

__device__ inline void gbar(int* line, int expected) {
    __syncthreads();
    if (threadIdx.x == 0) {
        __threadfence();  // release my block's writes device-wide
        int old = __hip_atomic_fetch_add(line, 1, __ATOMIC_RELAXED,
                                         __HIP_MEMORY_SCOPE_AGENT);
        if (old == expected - 1) {
            // last arriver: publish the go flag
            __hip_atomic_store(line + 8, 1, __ATOMIC_RELEASE,
                               __HIP_MEMORY_SCOPE_AGENT);
        } else {
            while (__hip_atomic_load(line + 8, __ATOMIC_RELAXED,
                                     __HIP_MEMORY_SCOPE_AGENT) == 0)
                __builtin_amdgcn_s_sleep(1);
        }
        __threadfence();  // acquire: discard stale cached lines
    }
    __syncthreads();
}

__device__ inline float wave_reduce(float s) {
#pragma unroll
    for (int off = 32; off > 0; off >>= 1) s += __shfl_down(s, off, 64);
    return s;
}

__global__ __launch_bounds__(NTHR) void mega_kernel(
    const float* __restrict__ features, const float* __restrict__ W_in,
    const float* __restrict__ b_in, const float* __restrict__ Ws,
    const float* __restrict__ bs, const float* __restrict__ W_out,
    const float* __restrict__ b_out, const int* __restrict__ src,
    const int* __restrict__ dst, float* __restrict__ out,
    int* __restrict__ ctr, int* __restrict__ deg, int* __restrict__ row_ptr,
    int* __restrict__ cursor, int* __restrict__ esrc, float* __restrict__ agg6,
    float* __restrict__ v,      // [2][512]
    float* __restrict__ gamma,  // [10]
    float* __restrict__ r) {    // [2][RPAD]
    __shared__ int sums[NTHR];
    const int blk = blockIdx.x;
    const int tid = threadIdx.x;

    if (blk < GRPA) {
        // ================= group A: backward weight chain =================
        const int g = blk * NTHR + tid;      // 0..32767
        const int w = g >> 6;                // 0..511 (one row per wave)
        const int lane = g & 63;
        if (g < 512) v[g] = W_out[g];        // v[0] = W_out column
        gbar(ctr + (CA + 0) * BAR_LINE, GRPA);
        int cur = 0;
        for (int l = DEPTH - 1; l >= 0; l--) {
            const float* Wrow = Ws + (size_t)l * 512 * 512 + (size_t)w * 512;
            const float* vin = v + cur * 512;
            float s = 0.f;
#pragma unroll
            for (int c = 0; c < 8; c++) s += Wrow[lane + c * 64] * vin[lane + c * 64];
            s = wave_reduce(s);
            if (lane == 0) v[(cur ^ 1) * 512 + w] = s;
            if (w == 511) {  // gamma[l] = bs[l] . vin
                const float* bl = bs + (size_t)l * 512;
                float t = 0.f;
#pragma unroll
                for (int c = 0; c < 8; c++) t += bl[lane + c * 64] * vin[lane + c * 64];
                t = wave_reduce(t);
                if (lane == 0) gamma[l] = t;
            }
            if (l > 0)  // last step's visibility is handled by the join barrier
                gbar(ctr + (CA + 1 + (DEPTH - 1 - l)) * BAR_LINE, GRPA);
            cur ^= 1;
        }
        // w~ now in v[0..511]
    } else {
        // ================= group B: CSR build + agg6 =================
        const int g = (blk - GRPA) * NTHR + tid;  // 0..98303
        if (g < N_NODES) deg[g] = 0;
        gbar(ctr + (CB + 0) * BAR_LINE, GRPB);
        for (int i = g; i < N_EDGES; i += GRPB * NTHR) atomicAdd(&deg[dst[i]], 1);
        gbar(ctr + (CB + 1) * BAR_LINE, GRPB);
        if (blk == GRPA) {
            // exclusive scan of deg[10000] by this block alone (512 thr x 20)
            const int CH = 20;
            int base = tid * CH;
            int local[CH];
            int s = 0;
#pragma unroll
            for (int i = 0; i < CH; i++) {
                int idx = base + i;
                int vv = (idx < N_NODES) ? deg[idx] : 0;
                local[i] = s;
                s += vv;
            }
            sums[tid] = s;
            __syncthreads();
            for (int off = 1; off < NTHR; off <<= 1) {
                int vv = (tid >= off) ? sums[tid - off] : 0;
                __syncthreads();
                sums[tid] += vv;
                __syncthreads();
            }
            int cb = (tid > 0) ? sums[tid - 1] : 0;
#pragma unroll
            for (int i = 0; i < CH; i++) {
                int idx = base + i;
                if (idx < N_NODES) {
                    int vv = cb + local[i];
                    row_ptr[idx] = vv;
                    cursor[idx] = vv;
                }
            }
            if (tid == NTHR - 1) row_ptr[N_NODES] = sums[NTHR - 1];
        }
        gbar(ctr + (CB + 2) * BAR_LINE, GRPB);
        for (int i = g; i < N_EDGES; i += GRPB * NTHR) {
            int p = atomicAdd(&cursor[dst[i]], 1);
            esrc[p] = src[i];
        }
        gbar(ctr + (CB + 3) * BAR_LINE, GRPB);
        // agg6: 8 lanes per node (6 active)
        {
            int node = g >> 3, c = g & 7;
            if (node < N_NODES && c < 6) {
                int s0 = row_ptr[node], e0 = row_ptr[node + 1];
                float a0 = 0.f, a1 = 0.f;
                int e = s0;
                for (; e + 2 <= e0; e += 2) {
                    a0 += features[esrc[e] * 6 + c];
                    a1 += features[esrc[e + 1] * 6 + c];
                }
                if (e < e0) a0 += features[esrc[e] * 6 + c];
                agg6[node * 6 + c] = a0 + a1;
            }
        }
    }

    // ================= join =================
    gbar(ctr + (CF + 0) * BAR_LINE, NBLK);

    // ================= input_z: r[0][n] = relu(agg6 W_in + b_in) . w~ =========
    {
        const int g = blk * NTHR + tid;
        const int wgid = g >> 6;
        const int lane = g & 63;
        const int nw = (NBLK * NTHR) >> 6;  // 2048 waves
        for (int node = wgid; node < N_NODES; node += nw) {
            float a[6];
#pragma unroll
            for (int k = 0; k < 6; k++) a[k] = agg6[node * 6 + k];
            float s = 0.f;
#pragma unroll
            for (int c8 = 0; c8 < 8; c8++) {
                int j = lane + c8 * 64;
                float t = b_in[j];
#pragma unroll
                for (int k = 0; k < 6; k++) t += a[k] * W_in[k * 512 + j];
                s += fmaxf(t, 0.f) * v[j];  // w~ = v[0]
            }
            s = wave_reduce(s);
            if (lane == 0) r[node] = s;
        }
    }
    gbar(ctr + (CF + 1) * BAR_LINE, NBLK);

    // ================= Horner: r <- A r + gamma[l] ; last adds b_out =========
    {
        const int g = blk * NTHR + tid;
        const int node = g >> 3;    // 8 lanes per node
        const int l8 = g & 7;
        int start = 0, end = 0;
        if (node < N_NODES) {
            start = row_ptr[node];
            end = row_ptr[node + 1];
        }
        int cur = 0;
        for (int l = 0; l < DEPTH; l++) {
            const float* rin = r + cur * RPAD;
            float s = 0.f;
            if (node < N_NODES) {
                for (int e = start + l8; e < end; e += 8) s += rin[esrc[e]];
            }
            s += __shfl_xor(s, 1, 64);
            s += __shfl_xor(s, 2, 64);
            s += __shfl_xor(s, 4, 64);
            if (node < N_NODES && l8 == 0) {
                float res = s + gamma[l];
                if (l == DEPTH - 1) out[node] = res + b_out[0];
                else r[(cur ^ 1) * RPAD + node] = res;
            }
            if (l < DEPTH - 1) gbar(ctr + (CF + 2 + l) * BAR_LINE, NBLK);
            cur ^= 1;
        }
    }
}

// ---------------- launch ----------------

extern "C" void kernel_launch(void* const* d_in, const int* in_sizes, int n_in,
                              void* d_out, int out_size, void* d_ws, size_t ws_size,
                              hipStream_t stream) {
    const float* features = (const float*)d_in[0];  // [10000, 6]
    const float* W_in     = (const float*)d_in[1];  // [6, 512]
    const float* b_in     = (const float*)d_in[2];  // [512]
    const float* Ws       = (const float*)d_in[3];  // [10, 512, 512]
    const float* bs       = (const float*)d_in[4];  // [10, 512]
    const float* W_out    = (const float*)d_in[5];  // [512, 1]
    const float* b_out    = (const float*)d_in[6];  // [1]
    const int*   src      = (const int*)d_in[7];    // [160000]
    const int*   dst      = (const int*)d_in[8];    // [160000]
    float* out = (float*)d_out;                     // [10000]

    char* p = (char*)d_ws;
    auto alloc = [&](size_t bytes) {
        char* r = p;
        p += (bytes + 255) & ~size_t(255);
        return r;
    };
    int* ctr     = (int*)alloc((size_t)NBAR * BAR_LINE * 4);
    int* deg     = (int*)alloc((size_t)N_NODES * 4);
    int* row_ptr = (int*)alloc((size_t)(N_NODES + 1) * 4);
    int* cursor  = (int*)alloc((size_t)N_NODES * 4);
    int* esrc    = (int*)alloc((size_t)N_EDGES * 4);
    float* agg6  = (float*)alloc((size_t)N_NODES * 6 * 4);
    float* v     = (float*)alloc(2 * 512 * 4);
    float* gamma = (float*)alloc(DEPTH * 4);
    float* r     = (float*)alloc((size_t)2 * RPAD * 4);

    zero_ctr_kernel<<<1, NBAR * BAR_LINE, 0, stream>>>(ctr);
    mega_kernel<<<NBLK, NTHR, 0, stream>>>(features, W_in, b_in, Ws, bs, W_out,
                                           b_out, src, dst, out, ctr, deg,
                                           row_ptr, cursor, esrc, agg6, v,
                                           gamma, r);
}

// Round 9
// 321.979 us; speedup vs baseline: 2.1911x; 1.2620x over previous
//
#include <hip/hip_runtime.h>

#define N_NODES 10000
#define N_EDGES 160000
#define DEPTH   10

#define NBLK    160       // 160 blocks x 1024 thr = 163840 threads >= N_EDGES
#define NTHR    1024
#define CHB     16        // blocks 0..15: weight chain; 16..159: feature scatter

// barrier lines: 64 B each: [0]=arrive ctr, [8]=go flag. Pre-zeroed per call.
#define BLINE   16
#define NBAR    32
#define B_CHAIN 0         // ids 0..9: chain handoffs (16 arrivals)
#define B_JOIN  10        // 160 arrivals
#define B_POSTZ 11
#define B_HOP   12        // +0..8

// ============================================================================
// R9: algebraic collapse (R6, exact) in ONE persistent kernel with
// cache-maintenance-free barriers:
//  - all cross-block data flows through FRESH buffers (each address written in
//    one phase, read only in later phases -> no stale L1/L2 copies possible),
//    published via device-scope atomics (execute at coherent LLC).
//  - barrier: s_waitcnt(0) drain + relaxed agent fetch_add + relaxed flag spin.
//    No __threadfence, no L2 invalidation (R7: 26 us/bar; R8: ~9 us/bar).
//  - Horner in scatter form (one thread per edge, perfectly balanced,
//    edge endpoints live in registers across all 10 hops); CSR build deleted.
//    r_{l+1} = A r_l + gamma_l*1  ==  rb_{l+1}[dst] += rb_l[src] + gamma_{l-1}
// ============================================================================

__global__ __launch_bounds__(256) void zero_kernel(int* bars, float* agg6, float* rbh) {
    int i = blockIdx.x * 256 + threadIdx.x;
    int stride = gridDim.x * 256;
    for (int k = i; k < NBAR * BLINE; k += stride) bars[k] = 0;
    for (int k = i; k < N_NODES * 6; k += stride) agg6[k] = 0.f;
    for (int k = i; k < 9 * N_NODES; k += stride) rbh[k] = 0.f;
}

__device__ inline void publish_f(float* p, float v) {
    __hip_atomic_store(p, v, __ATOMIC_RELAXED, __HIP_MEMORY_SCOPE_AGENT);
}

__device__ inline void bar(int* line, int expected) {
    __builtin_amdgcn_s_waitcnt(0);   // this wave's vmem (incl. atomics) done
    __syncthreads();                 // => whole block's vmem done
    if (threadIdx.x == 0) {
        int old = __hip_atomic_fetch_add(line, 1, __ATOMIC_RELAXED,
                                         __HIP_MEMORY_SCOPE_AGENT);
        if (old == expected - 1) {
            __hip_atomic_store(line + 8, 1, __ATOMIC_RELAXED,
                               __HIP_MEMORY_SCOPE_AGENT);
        } else {
            while (!__hip_atomic_load(line + 8, __ATOMIC_RELAXED,
                                      __HIP_MEMORY_SCOPE_AGENT))
                __builtin_amdgcn_s_sleep(1);
        }
    }
    __syncthreads();
    __asm__ volatile("" ::: "memory");  // no load hoisting across the barrier
}

__device__ inline float wave_reduce(float s) {
#pragma unroll
    for (int off = 32; off > 0; off >>= 1) s += __shfl_down(s, off, 64);
    return s;
}

__global__ __launch_bounds__(NTHR) void mega_kernel(
    const float* __restrict__ features, const float* __restrict__ W_in,
    const float* __restrict__ b_in, const float* __restrict__ Ws,
    const float* __restrict__ bs, const float* __restrict__ W_out,
    const float* __restrict__ b_out, const int* __restrict__ src,
    const int* __restrict__ dst, float* __restrict__ out,
    int* __restrict__ bars, float* __restrict__ agg6,
    float* __restrict__ v,      // [11][512]  fresh per chain step
    float* __restrict__ gamma,  // [10]
    float* __restrict__ rb0,    // [N] z
    float* __restrict__ rbh) {  // [9][N] fresh per hop
    const int blk = blockIdx.x;
    const int tid = threadIdx.x;

    // -------- preload Horner edge (registers, reused all 10 hops) --------
    const int e = blk * NTHR + tid;
    const bool on = (e < N_EDGES);
    int se = 0, de = 0;
    if (on) { se = src[e]; de = dst[e]; }

    if (blk < CHB) {
        // ================= chain: u_10=Wout; u_l = Ws[l] u_{l+1} ==========
        const int g = blk * NTHR + tid;          // 0..16383
        const int row = g >> 5;                  // 0..511 (32 lanes per row)
        const int c0 = g & 31;
        if (blk == 0 && tid < 512) publish_f(&v[tid], W_out[tid]);  // v[0]
        bar(bars + (B_CHAIN + 0) * BLINE, CHB);
#pragma unroll 1
        for (int t = 1; t <= DEPTH; t++) {
            const int l = DEPTH - t;             // v[t] = Ws[l] @ v[t-1]
            const float* vin = v + (t - 1) * 512;
            const float* Wrow = Ws + (size_t)l * 512 * 512 + (size_t)row * 512;
            float s = 0.f;
#pragma unroll
            for (int j = 0; j < 16; j++) s += Wrow[c0 + 32 * j] * vin[c0 + 32 * j];
#pragma unroll
            for (int off = 16; off > 0; off >>= 1) s += __shfl_xor(s, off, 64);
            if (c0 == 0) publish_f(&v[t * 512 + row], s);
            if (blk == 0 && tid < 64) {          // gamma[l] = bs[l] . v[t-1]
                float q = 0.f;
#pragma unroll
                for (int c = 0; c < 8; c++)
                    q += bs[(size_t)l * 512 + tid + 64 * c] * vin[tid + 64 * c];
                q = wave_reduce(q);
                if (tid == 0) publish_f(&gamma[l], q);
            }
            if (t < DEPTH) bar(bars + (B_CHAIN + t) * BLINE, CHB);
        }
        // v[10] = w~, published by join
    } else {
        // ================= feature scatter: agg6[d][c] += feat[s][c] ======
        const int g = (blk - CHB) * NTHR + tid;  // 0..147455
        for (int i = g; i < N_EDGES; i += (NBLK - CHB) * NTHR) {
            int s = src[i], d = dst[i];
#pragma unroll
            for (int c = 0; c < 6; c++)
                atomicAdd(&agg6[d * 6 + c], features[s * 6 + c]);
        }
    }

    // ================= join (chain + scatter both complete) ===============
    bar(bars + B_JOIN * BLINE, NBLK);

    // ===== input_z: rb0[n] = relu(agg6 W_in + b_in) . w~ ; out init =======
    {
        const int w = (blk * NTHR + tid) >> 6;   // 0..2559
        const int lane = tid & 63;
        const float* vt = v + DEPTH * 512;       // w~
        const float oinit = gamma[9] + b_out[0];
        for (int node = w; node < N_NODES; node += (NBLK * NTHR) >> 6) {
            float a[6];
#pragma unroll
            for (int k = 0; k < 6; k++) a[k] = agg6[node * 6 + k];
            float s = 0.f;
#pragma unroll
            for (int c = 0; c < 8; c++) {
                int j = lane + 64 * c;
                float t = b_in[j];
#pragma unroll
                for (int k = 0; k < 6; k++) t += a[k] * W_in[k * 512 + j];
                s += fmaxf(t, 0.f) * vt[j];
            }
            s = wave_reduce(s);
            if (lane == 0) {
                publish_f(&rb0[node], s);
                publish_f(&out[node], oinit);    // out accumulates hop 9 later
            }
        }
    }
    bar(bars + B_POSTZ * BLINE, NBLK);

    // ================= 10 scatter hops ====================================
#pragma unroll 1
    for (int l = 0; l < DEPTH; l++) {
        const float cl = (l == 0) ? 0.f : gamma[l - 1];
        const float* rin = (l == 0) ? rb0 : rbh + (size_t)(l - 1) * N_NODES;
        float* rout = (l == DEPTH - 1) ? out : rbh + (size_t)l * N_NODES;
        if (on) {
            float val = rin[se] + cl;
            atomicAdd(&rout[de], val);
        }
        if (l < DEPTH - 1) bar(bars + (B_HOP + l) * BLINE, NBLK);
    }
    // kernel end: dispatch-complete flush makes `out` (LLC) host-visible
}

// ---------------- launch ----------------

extern "C" void kernel_launch(void* const* d_in, const int* in_sizes, int n_in,
                              void* d_out, int out_size, void* d_ws, size_t ws_size,
                              hipStream_t stream) {
    const float* features = (const float*)d_in[0];  // [10000, 6]
    const float* W_in     = (const float*)d_in[1];  // [6, 512]
    const float* b_in     = (const float*)d_in[2];  // [512]
    const float* Ws       = (const float*)d_in[3];  // [10, 512, 512]
    const float* bs       = (const float*)d_in[4];  // [10, 512]
    const float* W_out    = (const float*)d_in[5];  // [512, 1]
    const float* b_out    = (const float*)d_in[6];  // [1]
    const int*   src      = (const int*)d_in[7];    // [160000]
    const int*   dst      = (const int*)d_in[8];    // [160000]
    float* out = (float*)d_out;                     // [10000]

    char* p = (char*)d_ws;
    auto alloc = [&](size_t bytes) {
        char* r = p;
        p += (bytes + 255) & ~size_t(255);
        return r;
    };
    int*   bars  = (int*)alloc((size_t)NBAR * BLINE * 4);
    float* agg6  = (float*)alloc((size_t)N_NODES * 6 * 4);
    float* v     = (float*)alloc((size_t)11 * 512 * 4);
    float* gamma = (float*)alloc(DEPTH * 4);
    float* rb0   = (float*)alloc((size_t)N_NODES * 4);
    float* rbh   = (float*)alloc((size_t)9 * N_NODES * 4);

    zero_kernel<<<256, 256, 0, stream>>>(bars, agg6, rbh);
    mega_kernel<<<NBLK, NTHR, 0, stream>>>(features, W_in, b_in, Ws, bs, W_out,
                                           b_out, src, dst, out, bars, agg6,
                                           v, gamma, rb0, rbh);
}

// Round 11
// 230.423 us; speedup vs baseline: 3.0617x; 1.3973x over previous
//
#include <hip/hip_runtime.h>

#define N_NODES 10000
#define N_EDGES 160000
#define DEPTH   10

#define NBLK    160
#define NTHR    512
#define CHB     16                 // blocks 0..15: weight chain
#define CSB     (NBLK - CHB)       // blocks 16..159: CSR build

#define BLINE   16                 // ints per 64-B barrier line: [0]=ctr,[8]=flag
#define B_CHAIN 0                  // 0..9  (16 arrivals)
#define B_CNT   10                 // 144 arrivals
#define B_SCAN  11                 // 144 arrivals
#define B_JOIN  12                 // 160 arrivals (heavy: reader-side fence)
#define B_POSTZ 13                 // 160
#define B_HOP   14                 // +0..8, 160
#define NBAR    24

// ============================================================================
// R11: algebraic collapse (R6, exact):
//   out = A^10 x1 w~ + sum_k gamma_k A^(10-k) 1 + b_out
// One persistent kernel built ONLY from mechanisms validated in R8/R9:
//  - light barrier: relaxed agent fetch_add + relaxed flag spin (R9);
//  - ALL cross-phase data published via agent-scope ATOMIC STORES to fresh,
//    never-before-read buffers (R9: v/gamma/rb) -> no stale L1/L2 possible,
//    no write-allocate false sharing (esrc now atomic-published too — R10's
//    plain-store esrc false-shared 64B lines across XCDs);
//  - gather-form z + hops (R6 math): 10k pub-stores/hop instead of R9's
//    1.6M HBM-RMW atomicAdds (which were 79.6 MB WRITE = the whole runtime);
//  - atomics only in CSR build (~320k), overlapped with the weight chain.
// ============================================================================

__global__ __launch_bounds__(256) void zero_kernel(int* p, int n) {
    int i = blockIdx.x * 256 + threadIdx.x;
    int st = gridDim.x * 256;
    for (int k = i; k < n; k += st) p[k] = 0;
}

__device__ inline void pub_f(float* p, float v) {  // write-through to LLC
    __hip_atomic_store(p, v, __ATOMIC_RELAXED, __HIP_MEMORY_SCOPE_AGENT);
}
__device__ inline void pub_i(int* p, int v) {
    __hip_atomic_store(p, v, __ATOMIC_RELAXED, __HIP_MEMORY_SCOPE_AGENT);
}

// light barrier (R9-validated): no cache maintenance
__device__ inline void bar(int* line, int expected) {
    __builtin_amdgcn_s_waitcnt(0);
    __syncthreads();
    if (threadIdx.x == 0) {
        int old = __hip_atomic_fetch_add(line, 1, __ATOMIC_RELAXED,
                                         __HIP_MEMORY_SCOPE_AGENT);
        if (old == expected - 1) {
            __hip_atomic_store(line + 8, 1, __ATOMIC_RELAXED,
                               __HIP_MEMORY_SCOPE_AGENT);
        } else {
            while (!__hip_atomic_load(line + 8, __ATOMIC_RELAXED,
                                      __HIP_MEMORY_SCOPE_AGENT))
                __builtin_amdgcn_s_sleep(1);
        }
    }
    __syncthreads();
    asm volatile("" ::: "memory");
}

// heavy barrier (join only): adds reader-side fence (discard any stale lines)
__device__ inline void bar_heavy(int* line, int expected) {
    __builtin_amdgcn_s_waitcnt(0);
    __syncthreads();
    if (threadIdx.x == 0) {
        __threadfence();  // writer-side: flush any dirty lines to LLC
        int old = __hip_atomic_fetch_add(line, 1, __ATOMIC_RELAXED,
                                         __HIP_MEMORY_SCOPE_AGENT);
        if (old == expected - 1) {
            __hip_atomic_store(line + 8, 1, __ATOMIC_RELAXED,
                               __HIP_MEMORY_SCOPE_AGENT);
        } else {
            while (!__hip_atomic_load(line + 8, __ATOMIC_RELAXED,
                                      __HIP_MEMORY_SCOPE_AGENT))
                __builtin_amdgcn_s_sleep(1);
        }
        __threadfence();  // reader-side: invalidate stale cached lines
    }
    __syncthreads();
    asm volatile("" ::: "memory");
}

__device__ inline float wave_reduce(float s) {
#pragma unroll
    for (int off = 32; off > 0; off >>= 1) s += __shfl_down(s, off, 64);
    return s;
}

__global__ __launch_bounds__(NTHR) void mega_kernel(
    const float* __restrict__ features, const float* __restrict__ W_in,
    const float* __restrict__ b_in, const float* __restrict__ Ws,
    const float* __restrict__ bs, const float* __restrict__ W_out,
    const float* __restrict__ b_out, const int* __restrict__ src,
    const int* __restrict__ dst, float* __restrict__ out,
    int* __restrict__ bars, int* __restrict__ deg, int* __restrict__ row_ptr,
    int* __restrict__ cursor, int* __restrict__ esrc,
    float* __restrict__ v,        // [11][512]  fresh per chain step
    float* __restrict__ gamma,    // [10]
    float* __restrict__ rb0,      // [N] z
    float* __restrict__ rbh) {    // [9][N] fresh per hop
    __shared__ int sums[NTHR];
    const int blk = blockIdx.x;
    const int tid = threadIdx.x;

    if (blk < CHB) {
        // ===== chain: u10 = Wout; u_l = Ws[l] @ u_{l+1}; gamma[l]=bs[l].u_{l+1}
        const int g = blk * NTHR + tid;   // 0..8191
        const int row = g >> 4;           // 0..511, 16 lanes per row
        const int c0 = g & 15;
        if (blk == 0 && tid < 512) pub_f(&v[tid], W_out[tid]);  // v[0] = u10
        bar(bars + (B_CHAIN + 0) * BLINE, CHB);
#pragma unroll 1
        for (int t = 1; t <= DEPTH; t++) {
            const int l = DEPTH - t;      // v[t] = Ws[l] @ v[t-1]
            const float* vin = v + (t - 1) * 512;
            const float* Wrow = Ws + (size_t)l * 512 * 512 + (size_t)row * 512;
            float s = 0.f;
#pragma unroll
            for (int j = 0; j < 32; j++) s += Wrow[c0 + 16 * j] * vin[c0 + 16 * j];
            s += __shfl_xor(s, 8, 16);
            s += __shfl_xor(s, 4, 16);
            s += __shfl_xor(s, 2, 16);
            s += __shfl_xor(s, 1, 16);
            if (c0 == 0) pub_f(&v[t * 512 + row], s);
            if (blk == 0 && tid < 64) {   // gamma[l] = bs[l] . v[t-1]
                float q = 0.f;
#pragma unroll
                for (int c = 0; c < 8; c++)
                    q += bs[(size_t)l * 512 + tid + 64 * c] * vin[tid + 64 * c];
                q = wave_reduce(q);
                if (tid == 0) pub_f(&gamma[l], q);
            }
            if (t < DEPTH) bar(bars + (B_CHAIN + t) * BLINE, CHB);
        }
    } else {
        // ===== CSR build (144 blocks) =====================================
        const int g = (blk - CHB) * NTHR + tid;
        const int stride = CSB * NTHR;    // 73728
        for (int i = g; i < N_EDGES; i += stride)
            atomicAdd(&deg[dst[i]], 1);   // agent scope -> LLC RMW
        bar(bars + B_CNT * BLINE, CSB);
        if (blk == CHB) {
            // exclusive scan of deg[10000]: 512 thr x 20
            const int CH = 20;
            int base = tid * CH;
            int local[CH];
            int s = 0;
#pragma unroll
            for (int i = 0; i < CH; i++) {
                int idx = base + i;
                int vv = (idx < N_NODES) ? deg[idx] : 0;  // fresh lines
                local[i] = s;
                s += vv;
            }
            sums[tid] = s;
            __syncthreads();
            for (int off = 1; off < NTHR; off <<= 1) {
                int vv = (tid >= off) ? sums[tid - off] : 0;
                __syncthreads();
                sums[tid] += vv;
                __syncthreads();
            }
            int cb = (tid > 0) ? sums[tid - 1] : 0;
#pragma unroll
            for (int i = 0; i < CH; i++) {
                int idx = base + i;
                if (idx < N_NODES) {
                    int vv = cb + local[i];
                    pub_i(&row_ptr[idx], vv);   // atomic-publish (no L2 dirty)
                    pub_i(&cursor[idx], vv);
                }
            }
            if (tid == NTHR - 1) pub_i(&row_ptr[N_NODES], sums[NTHR - 1]);
        }
        bar(bars + B_SCAN * BLINE, CSB);
        for (int i = g; i < N_EDGES; i += stride) {
            int p = atomicAdd(&cursor[dst[i]], 1);  // LLC RMW
            pub_i(&esrc[p], src[i]);                // atomic-publish: no
        }                                           // write-allocate/false-share
    }

    // ===== join: chain + CSR complete (heavy: reader-side fence) ==========
    bar_heavy(bars + B_JOIN * BLINE, NBLK);

    float gm[DEPTH];
#pragma unroll
    for (int l = 0; l < DEPTH; l++) gm[l] = gamma[l];  // fresh lines
    const float bout = b_out[0];
    const float* vt = v + DEPTH * 512;                 // w~

    // ===== z-phase: rb0[n] = relu(agg6(n) W_in + b_in) . w~  (one wave/node)
    {
        const int wv = (blk * NTHR + tid) >> 6;        // 0..1279
        const int lane = tid & 63;
        const int eslot = lane >> 3;                   // 0..7
        const int c = lane & 7;                        // col, active c<6
        for (int n = wv; n < N_NODES; n += (NBLK * NTHR) >> 6) {
            int s0 = row_ptr[n], e0 = row_ptr[n + 1];
            float a = 0.f;
            if (c < 6)
                for (int e = s0 + eslot; e < e0; e += 8)
                    a += features[esrc[e] * 6 + c];
            a += __shfl_xor(a, 8, 64);                 // reduce over eslot
            a += __shfl_xor(a, 16, 64);
            a += __shfl_xor(a, 32, 64);
            float a0 = __shfl(a, 0, 64), a1 = __shfl(a, 1, 64);
            float a2 = __shfl(a, 2, 64), a3 = __shfl(a, 3, 64);
            float a4 = __shfl(a, 4, 64), a5 = __shfl(a, 5, 64);
            float z = 0.f;
#pragma unroll
            for (int cc = 0; cc < 8; cc++) {
                int j = lane + 64 * cc;
                float t = b_in[j] + a0 * W_in[0 * 512 + j] + a1 * W_in[1 * 512 + j] +
                          a2 * W_in[2 * 512 + j] + a3 * W_in[3 * 512 + j] +
                          a4 * W_in[4 * 512 + j] + a5 * W_in[5 * 512 + j];
                z += fmaxf(t, 0.f) * vt[j];
            }
            z = wave_reduce(z);
            if (lane == 0) pub_f(&rb0[n], z);
        }
    }
    bar(bars + B_POSTZ * BLINE, NBLK);

    // ===== 10 Horner hops, gather form, 8 lanes per node ==================
    {
        const int g = blk * NTHR + tid;   // 0..81919
        const int node = g >> 3;          // 0..10239
        const int l8 = g & 7;
        const bool active = (node < N_NODES);
        int s0 = 0, e0 = 0;
        if (active) { s0 = row_ptr[node]; e0 = row_ptr[node + 1]; }
#pragma unroll 1
        for (int l = 0; l < DEPTH; l++) {
            const float* rin = (l == 0) ? rb0 : rbh + (size_t)(l - 1) * N_NODES;
            float s = 0.f;
            if (active)
                for (int e = s0 + l8; e < e0; e += 8) s += rin[esrc[e]];
            s += __shfl_xor(s, 1, 64);
            s += __shfl_xor(s, 2, 64);
            s += __shfl_xor(s, 4, 64);
            if (active && l8 == 0) {
                float res = s + gm[l];
                if (l == DEPTH - 1) out[node] = res + bout;
                else pub_f(&rbh[(size_t)l * N_NODES + node], res);
            }
            if (l < DEPTH - 1) bar(bars + (B_HOP + l) * BLINE, NBLK);
        }
    }
    // kernel-end release flush publishes `out`
}

// ---------------- launch ----------------

extern "C" void kernel_launch(void* const* d_in, const int* in_sizes, int n_in,
                              void* d_out, int out_size, void* d_ws, size_t ws_size,
                              hipStream_t stream) {
    const float* features = (const float*)d_in[0];  // [10000, 6]
    const float* W_in     = (const float*)d_in[1];  // [6, 512]
    const float* b_in     = (const float*)d_in[2];  // [512]
    const float* Ws       = (const float*)d_in[3];  // [10, 512, 512]
    const float* bs       = (const float*)d_in[4];  // [10, 512]
    const float* W_out    = (const float*)d_in[5];  // [512, 1]
    const float* b_out    = (const float*)d_in[6];  // [1]
    const int*   src      = (const int*)d_in[7];    // [160000]
    const int*   dst      = (const int*)d_in[8];    // [160000]
    float* out = (float*)d_out;                     // [10000]

    char* p = (char*)d_ws;
    auto alloc = [&](size_t bytes) {
        char* r = p;
        p += (bytes + 255) & ~size_t(255);
        return r;
    };
    // zeroed region (contiguous): bars + deg
    int* zbase   = (int*)p;
    int* bars    = (int*)alloc((size_t)NBAR * BLINE * 4);
    int* deg     = (int*)alloc((size_t)N_NODES * 4);
    int  nzero   = (int)(((int*)p) - zbase);
    int* row_ptr = (int*)alloc((size_t)(N_NODES + 1) * 4);
    int* cursor  = (int*)alloc((size_t)N_NODES * 4);
    int* esrc    = (int*)alloc((size_t)N_EDGES * 4);
    float* v     = (float*)alloc((size_t)11 * 512 * 4);
    float* gamma = (float*)alloc(DEPTH * 4);
    float* rb0   = (float*)alloc((size_t)N_NODES * 4);
    float* rbh   = (float*)alloc((size_t)9 * N_NODES * 4);

    zero_kernel<<<40, 256, 0, stream>>>(zbase, nzero);
    mega_kernel<<<NBLK, NTHR, 0, stream>>>(features, W_in, b_in, Ws, bs, W_out,
                                           b_out, src, dst, out, bars, deg,
                                           row_ptr, cursor, esrc, v, gamma,
                                           rb0, rbh);
}